// Round 1
// baseline (250.996 us; speedup 1.0000x reference)
//
#include <hip/hip_runtime.h>

#define BATCH 256
#define QN 64
#define HN 2048
#define H2 (HN / 2)   // 1024
#define RPW 4         // rows (batches) per wave in normalize

typedef float v4f __attribute__((ext_vector_type(4)));

// Kernel A: factor[k][h] = prod_{j>k} W[k][j][h] * prod_{i<k} W[i][k][h]
// One thread per (k, h2) -> 65536 threads = 256 blocks (1 per CU, 4 waves/CU).
// unroll 16: ~16 outstanding 512B loads/wave -> ~32 KB in flight/CU, well past
// the ~9 KB needed to cover ~900cy HBM latency at 24.6 GB/s/CU.
__global__ __launch_bounds__(256) void factor_kernel(const float* __restrict__ W,
                                                     float* __restrict__ factor) {
    int idx = blockIdx.x * blockDim.x + threadIdx.x;   // 0..65535
    int h2 = idx & (H2 - 1);
    int k  = idx >> 10;                                // idx / 1024 (wave-uniform)
    const float2* W2 = (const float2*)W;
    float2 p = make_float2(1.f, 1.f);
    #pragma unroll 16
    for (int j = k + 1; j < QN; ++j) {
        float2 w = W2[(size_t)(k * QN + j) * H2 + h2];
        p.x *= w.x; p.y *= w.y;
    }
    #pragma unroll 16
    for (int i = 0; i < k; ++i) {
        float2 w = W2[(size_t)(i * QN + k) * H2 + h2];
        p.x *= w.x; p.y *= w.y;
    }
    ((float2*)factor)[(size_t)k * H2 + h2] = p;
}

// Kernel B: one WAVE per (q, batch-group-of-4). Factor slice for q is loaded
// ONCE into registers and reused across 4 rows (kills 124 MiB of L2 re-reads).
// Next row's x is prefetched into registers while the current row reduces and
// stores, so every wave keeps ~8 KB of loads in flight through the whole body.
// Per-row math order is identical to the previous kernel (same absmax).
__global__ __launch_bounds__(256) void normalize_kernel(const float* __restrict__ x,
                                                        const float* __restrict__ factor,
                                                        float* __restrict__ out) {
    const int wid  = blockIdx.x * 4 + (threadIdx.x >> 6);   // 0..4095
    const int lane = threadIdx.x & 63;
    const int q    = wid & (QN - 1);
    const int b0   = (wid >> 6) * RPW;                      // batch group base

    const v4f* f4 = (const v4f*)(factor + (size_t)q * HN);
    v4f b[8];
    #pragma unroll
    for (int i = 0; i < 8; ++i)
        b[i] = f4[lane + 64 * i];

    const v4f* x4 = (const v4f*)x;
    v4f*       o4 = (v4f*)out;

    const size_t rowstride = (size_t)QN * (HN / 4);         // same q, next batch
    size_t row = ((size_t)b0 * QN + q) * (HN / 4);          // v4f units

    v4f cur[8], nxt[8];
    #pragma unroll
    for (int i = 0; i < 8; ++i)
        cur[i] = __builtin_nontemporal_load(&x4[row + lane + 64 * i]);

    #pragma unroll
    for (int r = 0; r < RPW; ++r) {
        // prefetch next row while this one computes
        if (r + 1 < RPW) {
            size_t nrow = row + rowstride;
            #pragma unroll
            for (int i = 0; i < 8; ++i)
                nxt[i] = __builtin_nontemporal_load(&x4[nrow + lane + 64 * i]);
        }

        float ss = 0.f;
        #pragma unroll
        for (int i = 0; i < 8; ++i) {
            cur[i] *= b[i];
            ss += cur[i].x * cur[i].x + cur[i].y * cur[i].y
                + cur[i].z * cur[i].z + cur[i].w * cur[i].w;
        }

        // wave-64 butterfly: every lane ends with the full row sum
        #pragma unroll
        for (int off = 32; off >= 1; off >>= 1)
            ss += __shfl_xor(ss, off, 64);

        float inv = 1.0f / fmaxf(sqrtf(ss), 1e-12f);

        #pragma unroll
        for (int i = 0; i < 8; ++i) {
            cur[i] *= inv;
            __builtin_nontemporal_store(cur[i], &o4[row + lane + 64 * i]);
        }

        if (r + 1 < RPW) {
            #pragma unroll
            for (int i = 0; i < 8; ++i)
                cur[i] = nxt[i];
            row += rowstride;
        }
    }
}

extern "C" void kernel_launch(void* const* d_in, const int* in_sizes, int n_in,
                              void* d_out, int out_size, void* d_ws, size_t ws_size,
                              hipStream_t stream) {
    const float* x = (const float*)d_in[0];
    const float* W = (const float*)d_in[1];
    float* out     = (float*)d_out;
    float* factor  = (float*)d_ws;   // QN*HN floats = 512 KB

    factor_kernel<<<(QN * H2) / 256, 256, 0, stream>>>(W, factor);
    normalize_kernel<<<(BATCH * QN) / (4 * RPW), 256, 0, stream>>>(x, factor, out);
}